// Round 3
// baseline (740.942 us; speedup 1.0000x reference)
//
#include <hip/hip_runtime.h>

#define HDIM 128

// ======================= CSR build =======================

__global__ __launch_bounds__(256) void k_count(const int* __restrict__ dst,
                                               int* __restrict__ cnt, int e) {
    int i = blockIdx.x * 256 + threadIdx.x;
    if (i < e) atomicAdd(&cnt[dst[i]], 1);
}

__global__ __launch_bounds__(256) void k_dinv(const int* __restrict__ cnt,
                                              float* __restrict__ dinv, int n) {
    int i = blockIdx.x * 256 + threadIdx.x;
    if (i < n) dinv[i] = rsqrtf((float)(cnt[i] + 1));   // +1 self-loop
}

// block-wise exclusive scan (256/block) + block sums
__global__ __launch_bounds__(256) void k_scan1(const int* __restrict__ cnt,
                                               int* __restrict__ offs,
                                               int* __restrict__ bsum, int n) {
    __shared__ int sm[256];
    int tid = threadIdx.x;
    int i = blockIdx.x * 256 + tid;
    int v = (i < n) ? cnt[i] : 0;
    sm[tid] = v;
    __syncthreads();
    for (int off = 1; off < 256; off <<= 1) {
        int t = (tid >= off) ? sm[tid - off] : 0;
        __syncthreads();
        sm[tid] += t;
        __syncthreads();
    }
    if (i < n) offs[i] = sm[tid] - v;            // exclusive
    if (tid == 255) bsum[blockIdx.x] = sm[255];  // block total
}

// single-block exclusive scan of block sums (nb <= 512)
__global__ __launch_bounds__(512) void k_scan2(int* __restrict__ bsum, int nb) {
    __shared__ int sm[512];
    int tid = threadIdx.x;
    int v = (tid < nb) ? bsum[tid] : 0;
    sm[tid] = v;
    __syncthreads();
    for (int off = 1; off < 512; off <<= 1) {
        int t = (tid >= off) ? sm[tid - off] : 0;
        __syncthreads();
        sm[tid] += t;
        __syncthreads();
    }
    if (tid < nb) bsum[tid] = sm[tid] - v;       // exclusive
}

__global__ __launch_bounds__(256) void k_scan3(int* __restrict__ offs,
                                               const int* __restrict__ bsum,
                                               int n, int e) {
    int i = blockIdx.x * 256 + threadIdx.x;
    if (i < n) offs[i] += bsum[blockIdx.x];
    if (i == 0) offs[n] = e;
}

__global__ __launch_bounds__(256) void k_fill(const int* __restrict__ src,
                                              const int* __restrict__ dst,
                                              const int* __restrict__ offs,
                                              int* __restrict__ cursor,
                                              int* __restrict__ csr, int e) {
    int i = blockIdx.x * 256 + threadIdx.x;
    if (i < e) {
        int d = dst[i];
        int p = offs[d] + atomicAdd(&cursor[d], 1);
        csr[p] = src[i];
    }
}

// =============== fused GEMM: g = dinv .* (A @ W) ===============
// 128x128 tile, 256 threads, 8x8 outputs/thread.

template<int K>
__global__ __launch_bounds__(256) void k_gemm(const float* __restrict__ A,
                                              const float* __restrict__ W,
                                              const float* __restrict__ dinv,
                                              float* __restrict__ g, int n)
{
    __shared__ float aT[32][132];
    __shared__ float wT[32][128];

    const int tid  = threadIdx.x;
    const int colg = tid & 15;
    const int rowg = tid >> 4;
    const int row0 = blockIdx.x * 128;

    float accr[8][8];
    #pragma unroll
    for (int i = 0; i < 8; i++)
        #pragma unroll
        for (int j = 0; j < 8; j++) accr[i][j] = 0.0f;

    for (int k0 = 0; k0 < K; k0 += 32) {
        __syncthreads();
        #pragma unroll
        for (int i = 0; i < 4; i++) {
            int idx = i * 256 + tid;
            int r   = idx >> 3;
            int kq  = idx & 7;
            float4 v = make_float4(0.f, 0.f, 0.f, 0.f);
            int grow = row0 + r;
            if (grow < n)
                v = *(const float4*)(A + (size_t)grow * K + k0 + kq * 4);
            aT[kq * 4 + 0][r] = v.x;
            aT[kq * 4 + 1][r] = v.y;
            aT[kq * 4 + 2][r] = v.z;
            aT[kq * 4 + 3][r] = v.w;
        }
        #pragma unroll
        for (int i = 0; i < 4; i++) {
            int idx = i * 256 + tid;
            int kr  = idx >> 5;
            int cq  = idx & 31;
            *(float4*)&wT[kr][cq * 4] =
                *(const float4*)(W + (size_t)(k0 + kr) * HDIM + cq * 4);
        }
        __syncthreads();

        #pragma unroll 8
        for (int kk = 0; kk < 32; kk++) {
            float4 a0 = *(const float4*)&aT[kk][rowg * 8];
            float4 a1 = *(const float4*)&aT[kk][rowg * 8 + 4];
            float4 w0 = *(const float4*)&wT[kk][colg * 8];
            float4 w1 = *(const float4*)&wT[kk][colg * 8 + 4];
            float av[8] = {a0.x, a0.y, a0.z, a0.w, a1.x, a1.y, a1.z, a1.w};
            float wv[8] = {w0.x, w0.y, w0.z, w0.w, w1.x, w1.y, w1.z, w1.w};
            #pragma unroll
            for (int i = 0; i < 8; i++)
                #pragma unroll
                for (int j = 0; j < 8; j++)
                    accr[i][j] = fmaf(av[i], wv[j], accr[i][j]);
        }
    }

    #pragma unroll
    for (int i = 0; i < 8; i++) {
        int row = row0 + rowg * 8 + i;
        if (row < n) {
            float di = dinv[row];
            size_t base = (size_t)row * HDIM + colg * 8;
            float4 o0, o1;
            o0.x = accr[i][0] * di; o0.y = accr[i][1] * di;
            o0.z = accr[i][2] * di; o0.w = accr[i][3] * di;
            o1.x = accr[i][4] * di; o1.y = accr[i][5] * di;
            o1.z = accr[i][6] * di; o1.w = accr[i][7] * di;
            *(float4*)(g + base)     = o0;
            *(float4*)(g + base + 4) = o1;
        }
    }
}

// =============== gather + finish: out = [relu](dinv*(g[d] + sum g[src]) + b) ===============
// 32 threads per node. Edge indices loaded coalesced into lanes, shfl-broadcast,
// 4-deep unrolled row accumulation for outstanding-miss depth.

template<bool RELU>
__global__ __launch_bounds__(256) void k_gather(const float* __restrict__ g,
                                                const int* __restrict__ csr,
                                                const int* __restrict__ offs,
                                                const float* __restrict__ dinv,
                                                const float* __restrict__ bias,
                                                float* __restrict__ out, int n)
{
    int t    = blockIdx.x * 256 + threadIdx.x;
    int node = t >> 5;
    int l    = t & 31;
    if (node >= n) return;

    int e0 = offs[node];
    int e1 = offs[node + 1];

    // self-loop term
    float4 acc = *(const float4*)(g + (size_t)node * HDIM + l * 4);

    for (int base = e0; base < e1; base += 32) {
        int cnt = e1 - base; if (cnt > 32) cnt = 32;
        // one coalesced load covers up to 32 edge indices for this node
        int idx = (base + l < e1) ? csr[base + l] : 0;

        int j = 0;
        for (; j + 4 <= cnt; j += 4) {
            int s0 = __shfl(idx, j + 0, 32);
            int s1 = __shfl(idx, j + 1, 32);
            int s2 = __shfl(idx, j + 2, 32);
            int s3 = __shfl(idx, j + 3, 32);
            float4 v0 = *(const float4*)(g + (size_t)s0 * HDIM + l * 4);
            float4 v1 = *(const float4*)(g + (size_t)s1 * HDIM + l * 4);
            float4 v2 = *(const float4*)(g + (size_t)s2 * HDIM + l * 4);
            float4 v3 = *(const float4*)(g + (size_t)s3 * HDIM + l * 4);
            acc.x += v0.x; acc.y += v0.y; acc.z += v0.z; acc.w += v0.w;
            acc.x += v1.x; acc.y += v1.y; acc.z += v1.z; acc.w += v1.w;
            acc.x += v2.x; acc.y += v2.y; acc.z += v2.z; acc.w += v2.w;
            acc.x += v3.x; acc.y += v3.y; acc.z += v3.z; acc.w += v3.w;
        }
        for (; j < cnt; j++) {
            int s = __shfl(idx, j, 32);
            float4 v = *(const float4*)(g + (size_t)s * HDIM + l * 4);
            acc.x += v.x; acc.y += v.y; acc.z += v.z; acc.w += v.w;
        }
    }

    float di  = dinv[node];
    float4 bb = *(const float4*)(bias + l * 4);
    float4 o;
    o.x = fmaf(di, acc.x, bb.x);
    o.y = fmaf(di, acc.y, bb.y);
    o.z = fmaf(di, acc.z, bb.z);
    o.w = fmaf(di, acc.w, bb.w);
    if (RELU) {
        o.x = fmaxf(o.x, 0.f); o.y = fmaxf(o.y, 0.f);
        o.z = fmaxf(o.z, 0.f); o.w = fmaxf(o.w, 0.f);
    }
    *(float4*)(out + (size_t)node * HDIM + l * 4) = o;
}

// ======================= launch =======================

extern "C" void kernel_launch(void* const* d_in, const int* in_sizes, int n_in,
                              void* d_out, int out_size, void* d_ws, size_t ws_size,
                              hipStream_t stream)
{
    const float* x  = (const float*)d_in[0];
    const int*   ei = (const int*)d_in[1];
    const float* W1 = (const float*)d_in[2];
    const float* b1 = (const float*)d_in[3];
    const float* W2 = (const float*)d_in[4];
    const float* b2 = (const float*)d_in[5];
    const float* W3 = (const float*)d_in[6];
    const float* b3 = (const float*)d_in[7];
    float* out = (float*)d_out;

    const int n = in_sizes[0] / 256;   // IN = 256
    const int E = in_sizes[1] / 2;
    const int* src = ei;
    const int* dst = ei + E;

    // workspace layout (bytes):
    //   dinv @0, cnt @512K (reused as cursor), offs @1M, bsum @1536K,
    //   csr @1600K (6.4MB), g @8M (51.2MB)
    char*  ws   = (char*)d_ws;
    float* dinv = (float*)(ws);
    int*   cnt  = (int*)(ws + (512 << 10));
    int*   offs = (int*)(ws + (1 << 20));
    int*   bsum = (int*)(ws + (1536 << 10));
    int*   csr  = (int*)(ws + (1600 << 10));
    float* g    = (float*)(ws + (8 << 20));

    dim3 blk(256);
    int ngrid = (n + 255) / 256;
    int egrid = (E + 255) / 256;

    // ---- CSR build + norms ----
    hipMemsetAsync(cnt, 0, (size_t)n * 4, stream);
    k_count<<<egrid, blk, 0, stream>>>(dst, cnt, E);
    k_dinv<<<ngrid, blk, 0, stream>>>(cnt, dinv, n);
    k_scan1<<<ngrid, blk, 0, stream>>>(cnt, offs, bsum, n);
    k_scan2<<<1, 512, 0, stream>>>(bsum, ngrid);
    k_scan3<<<ngrid, blk, 0, stream>>>(offs, bsum, n, E);
    hipMemsetAsync(cnt, 0, (size_t)n * 4, stream);   // reuse as cursor
    k_fill<<<egrid, blk, 0, stream>>>(src, dst, offs, cnt, csr, E);

    int gemm_grid = (n + 127) / 128;
    int gat_grid  = (int)(((size_t)n * 32 + 255) / 256);

    // layer 1 (K=256)
    k_gemm<256><<<gemm_grid, blk, 0, stream>>>(x, W1, dinv, g, n);
    k_gather<true><<<gat_grid, blk, 0, stream>>>(g, csr, offs, dinv, b1, out, n);
    // layer 2 (K=128)
    k_gemm<128><<<gemm_grid, blk, 0, stream>>>(out, W2, dinv, g, n);
    k_gather<true><<<gat_grid, blk, 0, stream>>>(g, csr, offs, dinv, b2, out, n);
    // layer 3 (K=128)
    k_gemm<128><<<gemm_grid, blk, 0, stream>>>(out, W3, dinv, g, n);
    k_gather<false><<<gat_grid, blk, 0, stream>>>(g, csr, offs, dinv, b3, out, n);
}

// Round 4
// 514.213 us; speedup vs baseline: 1.4409x; 1.4409x over previous
//
#include <hip/hip_runtime.h>

#define HDIM 128

typedef unsigned int uint;
typedef unsigned short ushort;

// round-to-nearest-even float -> bf16 bits
__device__ inline ushort f2bf(float f) {
    uint u = __float_as_uint(f);
    uint rounding = 0x7fffu + ((u >> 16) & 1u);
    return (ushort)((u + rounding) >> 16);
}

__device__ inline float4 bf4_to_f4(uint2 u) {
    float4 r;
    r.x = __uint_as_float(u.x << 16);
    r.y = __uint_as_float(u.x & 0xffff0000u);
    r.z = __uint_as_float(u.y << 16);
    r.w = __uint_as_float(u.y & 0xffff0000u);
    return r;
}

// ======================= CSR build =======================

// count in-degree AND record each edge's rank within its dst bucket
__global__ __launch_bounds__(256) void k_count(const int* __restrict__ dst,
                                               int* __restrict__ cnt,
                                               int* __restrict__ rank, int e) {
    int i = blockIdx.x * 256 + threadIdx.x;
    if (i < e) rank[i] = atomicAdd(&cnt[dst[i]], 1);
}

__global__ __launch_bounds__(256) void k_dinv(const int* __restrict__ cnt,
                                              float* __restrict__ dinv, int n) {
    int i = blockIdx.x * 256 + threadIdx.x;
    if (i < n) dinv[i] = rsqrtf((float)(cnt[i] + 1));   // +1 self-loop
}

// block-wise exclusive scan (256/block) + block sums
__global__ __launch_bounds__(256) void k_scan1(const int* __restrict__ cnt,
                                               int* __restrict__ offs,
                                               int* __restrict__ bsum, int n) {
    __shared__ int sm[256];
    int tid = threadIdx.x;
    int i = blockIdx.x * 256 + tid;
    int v = (i < n) ? cnt[i] : 0;
    sm[tid] = v;
    __syncthreads();
    for (int off = 1; off < 256; off <<= 1) {
        int t = (tid >= off) ? sm[tid - off] : 0;
        __syncthreads();
        sm[tid] += t;
        __syncthreads();
    }
    if (i < n) offs[i] = sm[tid] - v;            // exclusive
    if (tid == 255) bsum[blockIdx.x] = sm[255];  // block total
}

__global__ __launch_bounds__(512) void k_scan2(int* __restrict__ bsum, int nb) {
    __shared__ int sm[512];
    int tid = threadIdx.x;
    int v = (tid < nb) ? bsum[tid] : 0;
    sm[tid] = v;
    __syncthreads();
    for (int off = 1; off < 512; off <<= 1) {
        int t = (tid >= off) ? sm[tid - off] : 0;
        __syncthreads();
        sm[tid] += t;
        __syncthreads();
    }
    if (tid < nb) bsum[tid] = sm[tid] - v;       // exclusive
}

__global__ __launch_bounds__(256) void k_scan3(int* __restrict__ offs,
                                               const int* __restrict__ bsum,
                                               int n, int e) {
    int i = blockIdx.x * 256 + threadIdx.x;
    if (i < n) offs[i] += bsum[blockIdx.x];
    if (i == 0) offs[n] = e;
}

// atomic-free fill: position = offs[dst] + precomputed rank
__global__ __launch_bounds__(256) void k_fill(const int* __restrict__ src,
                                              const int* __restrict__ dst,
                                              const int* __restrict__ offs,
                                              const int* __restrict__ rank,
                                              int* __restrict__ csr, int e) {
    int i = blockIdx.x * 256 + threadIdx.x;
    if (i < e) {
        csr[offs[dst[i]] + rank[i]] = src[i];
    }
}

// =============== fused GEMM: g = bf16( dinv .* (A @ W) ) ===============
// 128x128 tile, 256 threads, 8x8 outputs/thread.

template<int K>
__global__ __launch_bounds__(256) void k_gemm(const float* __restrict__ A,
                                              const float* __restrict__ W,
                                              const float* __restrict__ dinv,
                                              ushort* __restrict__ g, int n)
{
    __shared__ float aT[32][132];
    __shared__ float wT[32][128];

    const int tid  = threadIdx.x;
    const int colg = tid & 15;
    const int rowg = tid >> 4;
    const int row0 = blockIdx.x * 128;

    float accr[8][8];
    #pragma unroll
    for (int i = 0; i < 8; i++)
        #pragma unroll
        for (int j = 0; j < 8; j++) accr[i][j] = 0.0f;

    for (int k0 = 0; k0 < K; k0 += 32) {
        __syncthreads();
        #pragma unroll
        for (int i = 0; i < 4; i++) {
            int idx = i * 256 + tid;
            int r   = idx >> 3;
            int kq  = idx & 7;
            float4 v = make_float4(0.f, 0.f, 0.f, 0.f);
            int grow = row0 + r;
            if (grow < n)
                v = *(const float4*)(A + (size_t)grow * K + k0 + kq * 4);
            aT[kq * 4 + 0][r] = v.x;
            aT[kq * 4 + 1][r] = v.y;
            aT[kq * 4 + 2][r] = v.z;
            aT[kq * 4 + 3][r] = v.w;
        }
        #pragma unroll
        for (int i = 0; i < 4; i++) {
            int idx = i * 256 + tid;
            int kr  = idx >> 5;
            int cq  = idx & 31;
            *(float4*)&wT[kr][cq * 4] =
                *(const float4*)(W + (size_t)(k0 + kr) * HDIM + cq * 4);
        }
        __syncthreads();

        #pragma unroll 8
        for (int kk = 0; kk < 32; kk++) {
            float4 a0 = *(const float4*)&aT[kk][rowg * 8];
            float4 a1 = *(const float4*)&aT[kk][rowg * 8 + 4];
            float4 w0 = *(const float4*)&wT[kk][colg * 8];
            float4 w1 = *(const float4*)&wT[kk][colg * 8 + 4];
            float av[8] = {a0.x, a0.y, a0.z, a0.w, a1.x, a1.y, a1.z, a1.w};
            float wv[8] = {w0.x, w0.y, w0.z, w0.w, w1.x, w1.y, w1.z, w1.w};
            #pragma unroll
            for (int i = 0; i < 8; i++)
                #pragma unroll
                for (int j = 0; j < 8; j++)
                    accr[i][j] = fmaf(av[i], wv[j], accr[i][j]);
        }
    }

    #pragma unroll
    for (int i = 0; i < 8; i++) {
        int row = row0 + rowg * 8 + i;
        if (row < n) {
            float di = dinv[row];
            uint4 pk;
            pk.x = (uint)f2bf(accr[i][0] * di) | ((uint)f2bf(accr[i][1] * di) << 16);
            pk.y = (uint)f2bf(accr[i][2] * di) | ((uint)f2bf(accr[i][3] * di) << 16);
            pk.z = (uint)f2bf(accr[i][4] * di) | ((uint)f2bf(accr[i][5] * di) << 16);
            pk.w = (uint)f2bf(accr[i][6] * di) | ((uint)f2bf(accr[i][7] * di) << 16);
            *(uint4*)(g + (size_t)row * HDIM + colg * 8) = pk;
        }
    }
}

// ===== gather + finish: out = [relu](dinv*(g[d] + sum g[src]) + b), g in bf16 =====
// 32 threads per node, 4 bf16 (8B) per lane.

template<bool RELU>
__global__ __launch_bounds__(256) void k_gather(const ushort* __restrict__ g,
                                                const int* __restrict__ csr,
                                                const int* __restrict__ offs,
                                                const float* __restrict__ dinv,
                                                const float* __restrict__ bias,
                                                float* __restrict__ out, int n)
{
    int t    = blockIdx.x * 256 + threadIdx.x;
    int node = t >> 5;
    int l    = t & 31;
    if (node >= n) return;

    int e0 = offs[node];
    int e1 = offs[node + 1];

    // self-loop term
    float4 acc = bf4_to_f4(*(const uint2*)(g + (size_t)node * HDIM + l * 4));

    int e = e0;
    for (; e + 4 <= e1; e += 4) {
        int s0 = csr[e], s1 = csr[e + 1], s2 = csr[e + 2], s3 = csr[e + 3];
        float4 v0 = bf4_to_f4(*(const uint2*)(g + (size_t)s0 * HDIM + l * 4));
        float4 v1 = bf4_to_f4(*(const uint2*)(g + (size_t)s1 * HDIM + l * 4));
        float4 v2 = bf4_to_f4(*(const uint2*)(g + (size_t)s2 * HDIM + l * 4));
        float4 v3 = bf4_to_f4(*(const uint2*)(g + (size_t)s3 * HDIM + l * 4));
        acc.x += v0.x + v1.x + v2.x + v3.x;
        acc.y += v0.y + v1.y + v2.y + v3.y;
        acc.z += v0.z + v1.z + v2.z + v3.z;
        acc.w += v0.w + v1.w + v2.w + v3.w;
    }
    for (; e < e1; e++) {
        int s = csr[e];
        float4 v = bf4_to_f4(*(const uint2*)(g + (size_t)s * HDIM + l * 4));
        acc.x += v.x; acc.y += v.y; acc.z += v.z; acc.w += v.w;
    }

    float di  = dinv[node];
    float4 bb = *(const float4*)(bias + l * 4);
    float4 o;
    o.x = fmaf(di, acc.x, bb.x);
    o.y = fmaf(di, acc.y, bb.y);
    o.z = fmaf(di, acc.z, bb.z);
    o.w = fmaf(di, acc.w, bb.w);
    if (RELU) {
        o.x = fmaxf(o.x, 0.f); o.y = fmaxf(o.y, 0.f);
        o.z = fmaxf(o.z, 0.f); o.w = fmaxf(o.w, 0.f);
    }
    *(float4*)(out + (size_t)node * HDIM + l * 4) = o;
}

// ======================= launch =======================

extern "C" void kernel_launch(void* const* d_in, const int* in_sizes, int n_in,
                              void* d_out, int out_size, void* d_ws, size_t ws_size,
                              hipStream_t stream)
{
    const float* x  = (const float*)d_in[0];
    const int*   ei = (const int*)d_in[1];
    const float* W1 = (const float*)d_in[2];
    const float* b1 = (const float*)d_in[3];
    const float* W2 = (const float*)d_in[4];
    const float* b2 = (const float*)d_in[5];
    const float* W3 = (const float*)d_in[6];
    const float* b3 = (const float*)d_in[7];
    float* out = (float*)d_out;

    const int n = in_sizes[0] / 256;   // IN = 256
    const int E = in_sizes[1] / 2;
    const int* src = ei;
    const int* dst = ei + E;

    // workspace layout (bytes):
    //   dinv @0 (400KB), cnt @512K, offs @1M, bsum @1536K,
    //   csr @1600K (6.4MB), rank @8M (6.4MB), g(bf16) @16M (25.6MB)
    char*   ws   = (char*)d_ws;
    float*  dinv = (float*)(ws);
    int*    cnt  = (int*)(ws + (512 << 10));
    int*    offs = (int*)(ws + (1 << 20));
    int*    bsum = (int*)(ws + (1536 << 10));
    int*    csr  = (int*)(ws + (1600 << 10));
    int*    rank = (int*)(ws + (8 << 20));
    ushort* g    = (ushort*)(ws + (16 << 20));

    dim3 blk(256);
    int ngrid = (n + 255) / 256;
    int egrid = (E + 255) / 256;

    // ---- CSR build + norms ----
    hipMemsetAsync(cnt, 0, (size_t)n * 4, stream);
    k_count<<<egrid, blk, 0, stream>>>(dst, cnt, rank, E);
    k_dinv<<<ngrid, blk, 0, stream>>>(cnt, dinv, n);
    k_scan1<<<ngrid, blk, 0, stream>>>(cnt, offs, bsum, n);
    k_scan2<<<1, 512, 0, stream>>>(bsum, ngrid);
    k_scan3<<<ngrid, blk, 0, stream>>>(offs, bsum, n, E);
    k_fill<<<egrid, blk, 0, stream>>>(src, dst, offs, rank, csr, E);

    int gemm_grid = (n + 127) / 128;
    int gat_grid  = (int)(((size_t)n * 32 + 255) / 256);

    // layer 1 (K=256)
    k_gemm<256><<<gemm_grid, blk, 0, stream>>>(x, W1, dinv, g, n);
    k_gather<true><<<gat_grid, blk, 0, stream>>>(g, csr, offs, dinv, b1, out, n);
    // layer 2 (K=128)
    k_gemm<128><<<gemm_grid, blk, 0, stream>>>(out, W2, dinv, g, n);
    k_gather<true><<<gat_grid, blk, 0, stream>>>(g, csr, offs, dinv, b2, out, n);
    // layer 3 (K=128)
    k_gemm<128><<<gemm_grid, blk, 0, stream>>>(out, W3, dinv, g, n);
    k_gather<false><<<gat_grid, blk, 0, stream>>>(g, csr, offs, dinv, b3, out, n);
}

// Round 5
// 403.768 us; speedup vs baseline: 1.8351x; 1.2735x over previous
//
#include <hip/hip_runtime.h>

#define HDIM 128

typedef unsigned int uint;
typedef unsigned short ushort;
typedef __attribute__((ext_vector_type(8))) short short8;
typedef __attribute__((ext_vector_type(4))) float f32x4;

// round-to-nearest-even float -> bf16 bits
__device__ inline ushort f2bf(float f) {
    uint u = __float_as_uint(f);
    uint rounding = 0x7fffu + ((u >> 16) & 1u);
    return (ushort)((u + rounding) >> 16);
}
__device__ inline float bf2f(ushort h) { return __uint_as_float(((uint)h) << 16); }

__device__ inline float4 bf4_to_f4(uint2 u) {
    float4 r;
    r.x = __uint_as_float(u.x << 16);
    r.y = __uint_as_float(u.x & 0xffff0000u);
    r.z = __uint_as_float(u.y << 16);
    r.w = __uint_as_float(u.y & 0xffff0000u);
    return r;
}

// ======================= CSR build =======================

__global__ __launch_bounds__(256) void k_count(const int* __restrict__ dst,
                                               int* __restrict__ cnt,
                                               int* __restrict__ rank, int e) {
    int i = blockIdx.x * 256 + threadIdx.x;
    if (i < e) rank[i] = atomicAdd(&cnt[dst[i]], 1);
}

__global__ __launch_bounds__(256) void k_dinv(const int* __restrict__ cnt,
                                              float* __restrict__ dinv, int n) {
    int i = blockIdx.x * 256 + threadIdx.x;
    if (i < n) dinv[i] = rsqrtf((float)(cnt[i] + 1));   // +1 self-loop
}

__global__ __launch_bounds__(256) void k_scan1(const int* __restrict__ cnt,
                                               int* __restrict__ offs,
                                               int* __restrict__ bsum, int n) {
    __shared__ int sm[256];
    int tid = threadIdx.x;
    int i = blockIdx.x * 256 + tid;
    int v = (i < n) ? cnt[i] : 0;
    sm[tid] = v;
    __syncthreads();
    for (int off = 1; off < 256; off <<= 1) {
        int t = (tid >= off) ? sm[tid - off] : 0;
        __syncthreads();
        sm[tid] += t;
        __syncthreads();
    }
    if (i < n) offs[i] = sm[tid] - v;
    if (tid == 255) bsum[blockIdx.x] = sm[255];
}

__global__ __launch_bounds__(512) void k_scan2(int* __restrict__ bsum, int nb) {
    __shared__ int sm[512];
    int tid = threadIdx.x;
    int v = (tid < nb) ? bsum[tid] : 0;
    sm[tid] = v;
    __syncthreads();
    for (int off = 1; off < 512; off <<= 1) {
        int t = (tid >= off) ? sm[tid - off] : 0;
        __syncthreads();
        sm[tid] += t;
        __syncthreads();
    }
    if (tid < nb) bsum[tid] = sm[tid] - v;
}

__global__ __launch_bounds__(256) void k_scan3(int* __restrict__ offs,
                                               const int* __restrict__ bsum,
                                               int n, int e) {
    int i = blockIdx.x * 256 + threadIdx.x;
    if (i < n) offs[i] += bsum[blockIdx.x];
    if (i == 0) offs[n] = e;
}

__global__ __launch_bounds__(256) void k_fill(const int* __restrict__ src,
                                              const int* __restrict__ dst,
                                              const int* __restrict__ offs,
                                              const int* __restrict__ rank,
                                              int* __restrict__ csr, int e) {
    int i = blockIdx.x * 256 + threadIdx.x;
    if (i < e) {
        csr[offs[dst[i]] + rank[i]] = src[i];
    }
}

// =============== W prep: split-transpose W[K][128] -> Wt_hi/Wt_lo [128][K] bf16 ===============

__global__ __launch_bounds__(256) void k_prep_w(const float* __restrict__ W,
                                                ushort* __restrict__ wt_hi,
                                                ushort* __restrict__ wt_lo, int K) {
    int idx = blockIdx.x * 256 + threadIdx.x;
    if (idx < K * HDIM) {
        int k = idx >> 7;       // row in W
        int c = idx & 127;      // col in W
        float v = W[idx];
        ushort h = f2bf(v);
        ushort l = f2bf(v - bf2f(h));
        wt_hi[(size_t)c * K + k] = h;
        wt_lo[(size_t)c * K + k] = l;
    }
}

// =============== MFMA GEMM: g = bf16( dinv .* (X @ W) ), split-bf16 ===============
// A-operand = W^T (from wt_hi/wt_lo), B-operand = X (split on the fly).
// Block: 128 x-rows, all 128 w-cols; 4 waves in 2x2 grid (64x64 each);
// 16 fragments/wave of 16x16x32; 3 mfma per fragment (hh, hl, lh).

template<int K>
__global__ __launch_bounds__(256) void k_mm(const float* __restrict__ X,
                                            const ushort* __restrict__ wt_hi,
                                            const ushort* __restrict__ wt_lo,
                                            const float* __restrict__ dinv,
                                            ushort* __restrict__ g, int n)
{
    __shared__ ushort xh[128][40];   // X hi  [row][k]   pad->40 (80B rows, 16B aligned)
    __shared__ ushort xl[128][40];   // X lo
    __shared__ ushort wh[128][40];   // W^T hi [wcol][k]
    __shared__ ushort wl[128][40];   // W^T lo

    const int tid  = threadIdx.x;
    const int wv   = tid >> 6;       // wave 0..3
    const int lane = tid & 63;
    const int r    = lane & 15;      // A-row / B-col / D-col index
    const int gq   = lane >> 4;      // k-group
    const int row0 = blockIdx.x * 128;

    const int srow  = tid >> 1;      // staging row (0..127)
    const int shalf = tid & 1;       // staging k-half (16 elems each)

    f32x4 acc[4][4];
    #pragma unroll
    for (int m = 0; m < 4; m++)
        #pragma unroll
        for (int nf = 0; nf < 4; nf++)
            acc[m][nf] = (f32x4){0.f, 0.f, 0.f, 0.f};

    const int xbase = (wv >> 1) * 64;   // x-row base for this wave
    const int wbase = (wv & 1) * 64;    // w-col base for this wave

    for (int k0 = 0; k0 < K; k0 += 32) {
        __syncthreads();
        // ---- stage X tile (fp32 -> split bf16) ----
        {
            float4 f0, f1, f2, f3;
            int grow = row0 + srow;
            if (grow < n) {
                const float4* p = (const float4*)(X + (size_t)grow * K + k0 + shalf * 16);
                f0 = p[0]; f1 = p[1]; f2 = p[2]; f3 = p[3];
            } else {
                f0 = f1 = f2 = f3 = make_float4(0.f, 0.f, 0.f, 0.f);
            }
            float v[16] = {f0.x, f0.y, f0.z, f0.w, f1.x, f1.y, f1.z, f1.w,
                           f2.x, f2.y, f2.z, f2.w, f3.x, f3.y, f3.z, f3.w};
            uint h[8], l[8];
            #pragma unroll
            for (int q = 0; q < 8; q++) {
                ushort h0 = f2bf(v[2 * q]), h1 = f2bf(v[2 * q + 1]);
                h[q] = (uint)h0 | ((uint)h1 << 16);
                ushort l0 = f2bf(v[2 * q] - bf2f(h0));
                ushort l1 = f2bf(v[2 * q + 1] - bf2f(h1));
                l[q] = (uint)l0 | ((uint)l1 << 16);
            }
            *(uint4*)&xh[srow][shalf * 16]     = make_uint4(h[0], h[1], h[2], h[3]);
            *(uint4*)&xh[srow][shalf * 16 + 8] = make_uint4(h[4], h[5], h[6], h[7]);
            *(uint4*)&xl[srow][shalf * 16]     = make_uint4(l[0], l[1], l[2], l[3]);
            *(uint4*)&xl[srow][shalf * 16 + 8] = make_uint4(l[4], l[5], l[6], l[7]);
        }
        // ---- stage W^T tile (already bf16 in global) ----
        {
            const ushort* ph = wt_hi + (size_t)srow * K + k0 + shalf * 16;
            uint4 a0 = *(const uint4*)ph;
            uint4 a1 = *(const uint4*)(ph + 8);
            *(uint4*)&wh[srow][shalf * 16]     = a0;
            *(uint4*)&wh[srow][shalf * 16 + 8] = a1;
            const ushort* pl = wt_lo + (size_t)srow * K + k0 + shalf * 16;
            uint4 b0 = *(const uint4*)pl;
            uint4 b1 = *(const uint4*)(pl + 8);
            *(uint4*)&wl[srow][shalf * 16]     = b0;
            *(uint4*)&wl[srow][shalf * 16 + 8] = b1;
        }
        __syncthreads();

        // ---- compute: keep all 4 B-frag pairs resident, loop A ----
        short8 bh[4], bl[4];
        #pragma unroll
        for (int nf = 0; nf < 4; nf++) {
            bh[nf] = *(const short8*)&xh[xbase + nf * 16 + r][gq * 8];
            bl[nf] = *(const short8*)&xl[xbase + nf * 16 + r][gq * 8];
        }
        #pragma unroll
        for (int m = 0; m < 4; m++) {
            short8 ah = *(const short8*)&wh[wbase + m * 16 + r][gq * 8];
            short8 al = *(const short8*)&wl[wbase + m * 16 + r][gq * 8];
            #pragma unroll
            for (int nf = 0; nf < 4; nf++) {
                acc[m][nf] = __builtin_amdgcn_mfma_f32_16x16x32_bf16(ah, bh[nf], acc[m][nf], 0, 0, 0);
                acc[m][nf] = __builtin_amdgcn_mfma_f32_16x16x32_bf16(ah, bl[nf], acc[m][nf], 0, 0, 0);
                acc[m][nf] = __builtin_amdgcn_mfma_f32_16x16x32_bf16(al, bh[nf], acc[m][nf], 0, 0, 0);
            }
        }
    }

    // ---- epilogue: D[wcol][xrow]; scale by dinv[xrow], store bf16 ----
    #pragma unroll
    for (int nf = 0; nf < 4; nf++) {
        int xrow = row0 + xbase + nf * 16 + r;
        if (xrow < n) {
            float di = dinv[xrow];
            #pragma unroll
            for (int m = 0; m < 4; m++) {
                int wcol = wbase + m * 16 + gq * 4;
                f32x4 a = acc[m][nf];
                uint2 pk;
                pk.x = (uint)f2bf(a[0] * di) | ((uint)f2bf(a[1] * di) << 16);
                pk.y = (uint)f2bf(a[2] * di) | ((uint)f2bf(a[3] * di) << 16);
                *(uint2*)(g + (size_t)xrow * HDIM + wcol) = pk;
            }
        }
    }
}

// ===== gather + finish: out = [relu](dinv*(g[d] + sum g[src]) + b), g in bf16 =====

template<bool RELU>
__global__ __launch_bounds__(256) void k_gather(const ushort* __restrict__ g,
                                                const int* __restrict__ csr,
                                                const int* __restrict__ offs,
                                                const float* __restrict__ dinv,
                                                const float* __restrict__ bias,
                                                float* __restrict__ out, int n)
{
    int t    = blockIdx.x * 256 + threadIdx.x;
    int node = t >> 5;
    int l    = t & 31;
    if (node >= n) return;

    int e0 = offs[node];
    int e1 = offs[node + 1];

    float4 acc = bf4_to_f4(*(const uint2*)(g + (size_t)node * HDIM + l * 4));

    int e = e0;
    for (; e + 4 <= e1; e += 4) {
        int s0 = csr[e], s1 = csr[e + 1], s2 = csr[e + 2], s3 = csr[e + 3];
        float4 v0 = bf4_to_f4(*(const uint2*)(g + (size_t)s0 * HDIM + l * 4));
        float4 v1 = bf4_to_f4(*(const uint2*)(g + (size_t)s1 * HDIM + l * 4));
        float4 v2 = bf4_to_f4(*(const uint2*)(g + (size_t)s2 * HDIM + l * 4));
        float4 v3 = bf4_to_f4(*(const uint2*)(g + (size_t)s3 * HDIM + l * 4));
        acc.x += v0.x + v1.x + v2.x + v3.x;
        acc.y += v0.y + v1.y + v2.y + v3.y;
        acc.z += v0.z + v1.z + v2.z + v3.z;
        acc.w += v0.w + v1.w + v2.w + v3.w;
    }
    for (; e < e1; e++) {
        int s = csr[e];
        float4 v = bf4_to_f4(*(const uint2*)(g + (size_t)s * HDIM + l * 4));
        acc.x += v.x; acc.y += v.y; acc.z += v.z; acc.w += v.w;
    }

    float di  = dinv[node];
    float4 bb = *(const float4*)(bias + l * 4);
    float4 o;
    o.x = fmaf(di, acc.x, bb.x);
    o.y = fmaf(di, acc.y, bb.y);
    o.z = fmaf(di, acc.z, bb.z);
    o.w = fmaf(di, acc.w, bb.w);
    if (RELU) {
        o.x = fmaxf(o.x, 0.f); o.y = fmaxf(o.y, 0.f);
        o.z = fmaxf(o.z, 0.f); o.w = fmaxf(o.w, 0.f);
    }
    *(float4*)(out + (size_t)node * HDIM + l * 4) = o;
}

// ======================= launch =======================

extern "C" void kernel_launch(void* const* d_in, const int* in_sizes, int n_in,
                              void* d_out, int out_size, void* d_ws, size_t ws_size,
                              hipStream_t stream)
{
    const float* x  = (const float*)d_in[0];
    const int*   ei = (const int*)d_in[1];
    const float* W1 = (const float*)d_in[2];
    const float* b1 = (const float*)d_in[3];
    const float* W2 = (const float*)d_in[4];
    const float* b2 = (const float*)d_in[5];
    const float* W3 = (const float*)d_in[6];
    const float* b3 = (const float*)d_in[7];
    float* out = (float*)d_out;

    const int n = in_sizes[0] / 256;   // IN = 256
    const int E = in_sizes[1] / 2;
    const int* src = ei;
    const int* dst = ei + E;

    // workspace layout (bytes):
    //   dinv @0, cnt @512K, offs @1M, bsum @1536K, csr @1600K (6.4MB),
    //   rank @8M (6.4MB), wt_hi @15M (64KB), wt_lo @15M+128K, g(bf16) @16M (25.6MB)
    char*   ws    = (char*)d_ws;
    float*  dinv  = (float*)(ws);
    int*    cnt   = (int*)(ws + (512 << 10));
    int*    offs  = (int*)(ws + (1 << 20));
    int*    bsum  = (int*)(ws + (1536 << 10));
    int*    csr   = (int*)(ws + (1600 << 10));
    int*    rank  = (int*)(ws + (8 << 20));
    ushort* wt_hi = (ushort*)(ws + (15 << 20));
    ushort* wt_lo = (ushort*)(ws + (15 << 20) + (128 << 10));
    ushort* g     = (ushort*)(ws + (16 << 20));

    dim3 blk(256);
    int ngrid = (n + 255) / 256;
    int egrid = (E + 255) / 256;

    // ---- CSR build + norms ----
    hipMemsetAsync(cnt, 0, (size_t)n * 4, stream);
    k_count<<<egrid, blk, 0, stream>>>(dst, cnt, rank, E);
    k_dinv<<<ngrid, blk, 0, stream>>>(cnt, dinv, n);
    k_scan1<<<ngrid, blk, 0, stream>>>(cnt, offs, bsum, n);
    k_scan2<<<1, 512, 0, stream>>>(bsum, ngrid);
    k_scan3<<<ngrid, blk, 0, stream>>>(offs, bsum, n, E);
    k_fill<<<egrid, blk, 0, stream>>>(src, dst, offs, rank, csr, E);

    int mm_grid  = (n + 127) / 128;
    int gat_grid = (int)(((size_t)n * 32 + 255) / 256);

    // layer 1 (K=256)
    k_prep_w<<<(256 * HDIM + 255) / 256, blk, 0, stream>>>(W1, wt_hi, wt_lo, 256);
    k_mm<256><<<mm_grid, blk, 0, stream>>>(x, wt_hi, wt_lo, dinv, g, n);
    k_gather<true><<<gat_grid, blk, 0, stream>>>(g, csr, offs, dinv, b1, out, n);
    // layer 2 (K=128)
    k_prep_w<<<(128 * HDIM + 255) / 256, blk, 0, stream>>>(W2, wt_hi, wt_lo, 128);
    k_mm<128><<<mm_grid, blk, 0, stream>>>(out, wt_hi, wt_lo, dinv, g, n);
    k_gather<true><<<gat_grid, blk, 0, stream>>>(g, csr, offs, dinv, b2, out, n);
    // layer 3 (K=128)
    k_prep_w<<<(128 * HDIM + 255) / 256, blk, 0, stream>>>(W3, wt_hi, wt_lo, 128);
    k_mm<128><<<mm_grid, blk, 0, stream>>>(out, wt_hi, wt_lo, dinv, g, n);
    k_gather<false><<<gat_grid, blk, 0, stream>>>(g, csr, offs, dinv, b3, out, n);
}